// Round 21
// baseline (229.367 us; speedup 1.0000x reference)
//
#include <hip/hip_runtime.h>
#include <hip/hip_fp16.h>
#include <math.h>

#define BN_EPS 1e-5f

typedef _Float16 h2v __attribute__((ext_vector_type(2)));

__device__ __forceinline__ float max3f(float a, float b, float c) {
    return fmaxf(fmaxf(a, b), c);
}
__device__ __forceinline__ float fdot2u(uint32_t a, uint32_t b, float c) {
    union U { uint32_t u; h2v h; } ua, ub;
    ua.u = a; ub.u = b;
    return __builtin_amdgcn_fdot2(ua.h, ub.h, c, false);
}
__device__ __forceinline__ uint32_t pack2(float a, float b) {
    union U { uint32_t u; h2v h; } x;
    x.h.x = (_Float16)a; x.h.y = (_Float16)b; return x.u;
}

// One block per PLANE PAIR. 1024 blocks x 512 threads = 4 blocks/CU, all
// resident. Pipeline: A0 | B0 | {A1 (HBM reads) INTERLEAVED with C0 (HBM
// writes)} | B1 | C1. A||C doubles memory-level parallelism in the overlap
// window and is register-light (unlike B||C which spilled in r16/r17):
// A live-set = ring(12)+hist(16); C chunk = transient load-mul-store,
// indices recomputed inline, sched_barrier(0) fences stop collective
// hoisting of the 18 x4 loads (the r16 spill mechanism).
__global__ __launch_bounds__(512, 8)
void mra_fused(const float* __restrict__ x,
               const float* __restrict__ wh1,
               const float* __restrict__ wv1,
               const float* __restrict__ wh2,
               const float* __restrict__ wv2,
               const float* __restrict__ bng,
               const float* __restrict__ bnb,
               const float* __restrict__ bnm,
               const float* __restrict__ bnv,
               float* __restrict__ out)
{
    __shared__ __align__(16) __half sxp_h[76][84];   // x_tem (reused per plane)
    __shared__ __align__(16) __half gate_h[64][72];  // gate (reused per plane)
    __shared__ __align__(16) uint32_t wtab[2][13][12];

    const int bid  = blockIdx.x;        // 0..1023
    const int p0g  = bid << 1;
    const int c0   = p0g & 255;         // even; slot-1 channel = c0+1
    const int tid  = threadIdx.x;
    const int lane = tid & 63;
    const int w    = tid >> 6;          // 0..7
    const float* __restrict__ xp0 = x   + (size_t)p0g * 36864;
    const float* __restrict__ xp1 = xp0 + 36864;
    float* __restrict__       op0 = out + (size_t)p0g * 36864;
    float* __restrict__       op1 = op0 + 36864;

    // ---- zero x_tem plane ----
    {
        int* z = (int*)&sxp_h[0][0];
        const int nInt = (76 * 84 * 2) / 4;   // 3192
        #pragma unroll
        for (int i = 0; i < 7; ++i) {
            const int idx = tid + (i << 9);
            if (idx < nInt) z[idx] = 0;
        }
    }
    // ---- pack fp16 weight-pair tables for both channels ----
    if (tid < 26) {
        const int tabi = tid / 13;
        const int er   = tid - 13 * tabi;
        const int e    = er - 6;
        const int cc   = c0 + tabi;
        const float* wh1p = wh1 + cc * 33;
        const float* wv1p = wv1 + cc * 33;
        const float* wh2p = wh2 + cc * 33;
        const float* wv2p = wv2 + cc * 33;
        uint32_t* wr = wtab[tabi][er];
        #pragma unroll
        for (int s = 0; s < 12; ++s) wr[s] = 0;
        if (e >= -5 && e <= 5) {
            const float* a1 = wh1p + (e + 5) * 3;
            wr[0] = pack2(a1[0], a1[1]); wr[1] = pack2(a1[2], 0.f);
            const float* a2 = wh2p + (e + 5) * 3;
            wr[2] = pack2(a2[0], a2[1]); wr[3] = pack2(a2[2], 0.f);
        }
        if (e >= -4 && e <= 4) {
            wr[4] = pack2(wv2p[4 - e], wv2p[16 - e]);
            wr[5] = pack2(wv2p[28 - e], 0.f);
        } else if (e == 5)  wr[4] = pack2(wv2p[11], wv2p[23]);
        else if (e == -5)   wr[4] = pack2(wv2p[9],  wv2p[21]);
        else if (e == 6)    wr[4] = pack2(wv2p[22], 0.f);
        else                wr[4] = pack2(wv2p[10], 0.f);   // e == -6
        if (e >= -1 && e <= 1) {
            const float* a3 = wv1p + (e + 1) * 11;
            wr[6]  = pack2(a3[0], a3[1]); wr[7]  = pack2(a3[2], a3[3]);
            wr[8]  = pack2(a3[4], a3[5]); wr[9]  = pack2(a3[6], a3[7]);
            wr[10] = pack2(a3[8], a3[9]); wr[11] = pack2(a3[10], 0.f);
        }
    }
    __syncthreads();

    // ---- C chunk: indices recomputed inline (ch compile-time) ----
    auto cChunk = [&](int ch, const float4* __restrict__ x4,
                      float4* __restrict__ o4) {
        const int j    = ch % 3;
        const int u    = ch / 3;
        const int idx0 = lane + (j << 6);            // 0..191
        const int rl   = idx0 / 48;                  // 0..3
        const int k0   = idx0 - rl * 48;             // 0..47
        const int row_l = rl + (u << 2);             // 0..23
        const int idx  = w * 1152 + lane + (ch << 6);
        const int gr   = (w << 3) + row_l / 3;       // gate row 8w..8w+7
        const int jb   = k0 << 2;
        const int gc   = jb / 3;
        const int rr   = jb - 3 * gc;
        const float g0 = __half2float(gate_h[gr][gc]);
        const float g1 = __half2float(gate_h[gr][gc + 1]);
        const float4 xv = x4[idx];
        float4 ov;
        const float s1 = (rr == 2) ? g1 : g0;
        const float s2 = (rr >= 1) ? g1 : g0;
        ov.x = xv.x * g0;
        ov.y = xv.y * s1;
        ov.z = xv.z * s2;
        ov.w = xv.w * g1;
        o4[idx] = ov;
    };

    // ---- Phase B iteration (one e-row of all four convs, fdot2) ----
    const int p  = tid >> 3;
    const int q0 = (tid & 7) << 3;

    auto bIter = [&](int e, const uint32_t* __restrict__ wrowu, float* acc) {
        const uint2* drow = (const uint2*)&sxp_h[p + e + 6][q0];
        uint32_t du[12], su[11];
        #pragma unroll
        for (int u2 = 0; u2 < 6; ++u2) {
            const uint2 t = drow[u2];
            du[2 * u2] = t.x; du[2 * u2 + 1] = t.y;
        }
        #pragma unroll
        for (int u = 0; u < 11; ++u)
            su[u] = __builtin_amdgcn_alignbit(du[u + 1], du[u], 16);

        const uint2* wrow = (const uint2*)wrowu;
        const uint2 wa = wrow[0], wb = wrow[1], wc = wrow[2];

        auto RUN3 = [&](float a, int j0, uint32_t pA, uint32_t pB) -> float {
            const int u = j0 >> 1;
            if (j0 & 1) { a = fdot2u(su[u], pA, a); a = fdot2u(su[u + 1], pB, a); }
            else        { a = fdot2u(du[u], pA, a); a = fdot2u(du[u + 1], pB, a); }
            return a;
        };
        auto RUN1 = [&](float a, int j0, uint32_t pA) -> float {
            const int u = j0 >> 1;
            return (j0 & 1) ? fdot2u(su[u], pA, a) : fdot2u(du[u], pA, a);
        };

        if (e >= -5 && e <= 5) {
            #pragma unroll
            for (int i = 0; i < 8; ++i) {
                acc[i] = RUN3(acc[i], i + 7, wa.x, wa.y);        // x_h1
                acc[i] = RUN3(acc[i], i + 7 - e, wb.x, wb.y);    // x_h2
            }
        }
        if (e >= -4 && e <= 4) {                                  // x_w2
            #pragma unroll
            for (int i = 0; i < 8; ++i) acc[i] = RUN3(acc[i], i + 7 - e, wc.x, wc.y);
        } else if (e == 5) {
            #pragma unroll
            for (int i = 0; i < 8; ++i) acc[i] = RUN1(acc[i], i + 3, wc.x);
        } else if (e == -5) {
            #pragma unroll
            for (int i = 0; i < 8; ++i) acc[i] = RUN1(acc[i], i + 12, wc.x);
        } else if (e == 6) {
            #pragma unroll
            for (int i = 0; i < 8; ++i) acc[i] = RUN1(acc[i], i + 3, wc.x);
        } else {  // e == -6
            #pragma unroll
            for (int i = 0; i < 8; ++i) acc[i] = RUN1(acc[i], i + 13, wc.x);
        }
        if (e >= -1 && e <= 1) {                                  // x_w1
            const uint2 wd = wrow[3], we_ = wrow[4], wf_ = wrow[5];
            const uint32_t wp[6] = {wd.x, wd.y, we_.x, we_.y, wf_.x, wf_.y};
            #pragma unroll
            for (int i = 0; i < 8; ++i) {
                const int j0 = i + 3;
                const int u  = j0 >> 1;
                float a = acc[i];
                #pragma unroll
                for (int kk = 0; kk < 6; ++kk)
                    a = (j0 & 1) ? fdot2u(su[u + kk], wp[kk], a)
                                 : fdot2u(du[u + kk], wp[kk], a);
                acc[i] = a;
            }
        }
    };

    auto bnStore = [&](const float* acc, int cc) {
        const float inv = bng[cc] * rsqrtf(bnv[cc] + BN_EPS);
        const float mu  = bnm[cc];
        const float bt  = bnb[cc];
        #pragma unroll
        for (int i = 0; i < 4; ++i) {
            const float a0 = (acc[2 * i]     - mu) * inv + bt;
            const float a1 = (acc[2 * i + 1] - mu) * inv + bt;
            const float g0 = 1.0f / (1.0f + __expf(-a0));
            const float g1 = 1.0f / (1.0f + __expf(-a1));
            *(__half2*)(&gate_h[p][q0 + 2 * i]) = __floats2half2_rn(g0, g1);
        }
    };

    // ================= pipeline =================
    // ---- A0: plain ----
    {
        const int P0  = w << 3;
        const int r0  = 3 * P0 - 2;
        const int col = 3 * lane;

        float c0r[4], c1r[4], c2r[4];
        auto issue = [&](int k, int s) {
            int r = r0 + k;
            r = r < 0 ? 0 : (r > 191 ? 191 : r);
            const float* rp = xp0 + r * 192 + col;
            c0r[s] = rp[0]; c1r[s] = rp[1]; c2r[s] = rp[2];
        };
        issue(0, 0); issue(1, 1); issue(2, 2); issue(3, 3);

        float h[3][4], hb[3], hbp = 0.f;

        #pragma unroll
        for (int k = 0; k < 27; ++k) {
            const int s = k & 3;
            const float cc0 = c0r[s], cc1 = c1r[s], cc2 = c2r[s];
            if (k + 4 < 27) issue(k + 4, s);

            float xm2 = __shfl_up(cc1, 1);
            float xm1 = __shfl_up(cc2, 1);
            float xp3 = __shfl_down(cc0, 1);
            if (lane == 0)  xm1 = cc0;
            if (lane == 63) xp3 = cc2;

            const float hm_m1 = max3f(xm2, xm1, cc0);
            const float hm_0  = max3f(xm1, cc0, cc1);
            const float hm_1  = max3f(cc0, cc1, cc2);
            const float hm_2  = max3f(cc1, cc2, xp3);

            float* hk = h[k % 3];
            hk[0] = (lane == 0) ? hm_1 : hm_m1;
            hk[1] = hm_0; hk[2] = hm_1; hk[3] = hm_2;

            if (k >= 2) {
                const float* a = h[(k - 2) % 3];
                const float* b = h[(k - 1) % 3];
                const float* d = h[k % 3];
                const float e4 =
                      0.125f * max3f(a[0], b[0], d[0])
                    + 0.375f * max3f(a[1], b[1], d[1])
                    + 0.375f * max3f(a[2], b[2], d[2])
                    + 0.125f * max3f(a[3], b[3], d[3]);
                if (k == 2) hbp = e4;
                else {
                    hb[k % 3] = e4;
                    if (k % 3 == 2) {
                        const int i = (k - 5) / 3;
                        float a_out;
                        if (i == 0 && w == 0)
                            a_out = 0.375f * hb[0] + 0.5f * hb[1] + 0.125f * hb[2];
                        else
                            a_out = 0.125f * hbp + 0.375f * hb[0]
                                  + 0.375f * hb[1] + 0.125f * hb[2];
                        hbp = hb[2];
                        sxp_h[(w << 3) + i + 6][lane + 8] = __float2half(a_out);
                    }
                }
            }
        }
    }
    __syncthreads();                   // sxp(p0) ready

    // ---- B0 -> gate(p0) ----
    {
        float acc[8];
        #pragma unroll
        for (int i = 0; i < 8; ++i) acc[i] = 0.f;
        #pragma unroll
        for (int e = -6; e <= 6; ++e) bIter(e, wtab[0][e + 6], acc);
        bnStore(acc, c0);
    }
    __syncthreads();                   // all B0 sxp reads done before A1 writes

    // ---- {A1 || C0}: plane-1 pooling reads interleaved with plane-0 output ----
    {
        const float4* __restrict__ x40 = (const float4*)xp0;
        float4* __restrict__       o40 = (float4*)op0;
        const int P0  = w << 3;
        const int r0  = 3 * P0 - 2;
        const int col = 3 * lane;

        float c0r[4], c1r[4], c2r[4];
        auto issue = [&](int k, int s) {
            int r = r0 + k;
            r = r < 0 ? 0 : (r > 191 ? 191 : r);
            const float* rp = xp1 + r * 192 + col;
            c0r[s] = rp[0]; c1r[s] = rp[1]; c2r[s] = rp[2];
        };
        issue(0, 0); issue(1, 1); issue(2, 2); issue(3, 3);

        float h[3][4], hb[3], hbp = 0.f;

        #pragma unroll
        for (int k = 0; k < 27; ++k) {
            const int s = k & 3;
            const float cc0 = c0r[s], cc1 = c1r[s], cc2 = c2r[s];
            if (k + 4 < 27) issue(k + 4, s);

            float xm2 = __shfl_up(cc1, 1);
            float xm1 = __shfl_up(cc2, 1);
            float xp3 = __shfl_down(cc0, 1);
            if (lane == 0)  xm1 = cc0;
            if (lane == 63) xp3 = cc2;

            const float hm_m1 = max3f(xm2, xm1, cc0);
            const float hm_0  = max3f(xm1, cc0, cc1);
            const float hm_1  = max3f(cc0, cc1, cc2);
            const float hm_2  = max3f(cc1, cc2, xp3);

            float* hk = h[k % 3];
            hk[0] = (lane == 0) ? hm_1 : hm_m1;
            hk[1] = hm_0; hk[2] = hm_1; hk[3] = hm_2;

            if (k >= 2) {
                const float* a = h[(k - 2) % 3];
                const float* b = h[(k - 1) % 3];
                const float* d = h[k % 3];
                const float e4 =
                      0.125f * max3f(a[0], b[0], d[0])
                    + 0.375f * max3f(a[1], b[1], d[1])
                    + 0.375f * max3f(a[2], b[2], d[2])
                    + 0.125f * max3f(a[3], b[3], d[3]);
                if (k == 2) hbp = e4;
                else {
                    hb[k % 3] = e4;
                    if (k % 3 == 2) {
                        const int i = (k - 5) / 3;
                        float a_out;
                        if (i == 0 && w == 0)
                            a_out = 0.375f * hb[0] + 0.5f * hb[1] + 0.125f * hb[2];
                        else
                            a_out = 0.125f * hbp + 0.375f * hb[0]
                                  + 0.375f * hb[1] + 0.125f * hb[2];
                        hbp = hb[2];
                        sxp_h[(w << 3) + i + 6][lane + 8] = __float2half(a_out);
                    }
                }
            }
            // interleave one C0 chunk per iteration, k = 5..22
            if (k >= 5 && k < 23) {
                __builtin_amdgcn_sched_barrier(0);
                cChunk(k - 5, x40, o40);
                __builtin_amdgcn_sched_barrier(0);
            }
        }
    }
    __syncthreads();                   // sxp(p1) ready; C0 gate reads drained

    // ---- B1 -> gate(p1) (reuses gate_h) ----
    {
        float acc[8];
        #pragma unroll
        for (int i = 0; i < 8; ++i) acc[i] = 0.f;
        #pragma unroll
        for (int e = -6; e <= 6; ++e) bIter(e, wtab[1][e + 6], acc);
        bnStore(acc, c0 + 1);
    }
    __builtin_amdgcn_wave_barrier();   // own-wave gate writes before C1 reads

    // ---- C1 ----
    {
        const float4* __restrict__ x41 = (const float4*)xp1;
        float4* __restrict__       o41 = (float4*)op1;
        #pragma unroll
        for (int ch = 0; ch < 18; ++ch) cChunk(ch, x41, o41);
    }
}

extern "C" void kernel_launch(void* const* d_in, const int* in_sizes, int n_in,
                              void* d_out, int out_size, void* d_ws, size_t ws_size,
                              hipStream_t stream) {
    const float* x   = (const float*)d_in[0];
    const float* wh1 = (const float*)d_in[1];
    const float* wv1 = (const float*)d_in[2];
    const float* wh2 = (const float*)d_in[3];
    const float* wv2 = (const float*)d_in[4];
    const float* g   = (const float*)d_in[5];
    const float* b   = (const float*)d_in[6];
    const float* m   = (const float*)d_in[7];
    const float* v   = (const float*)d_in[8];

    mra_fused<<<dim3(1024), dim3(512), 0, stream>>>(
        x, wh1, wv1, wh2, wv2, g, b, m, v, (float*)d_out);
}

// Round 22
// 156.301 us; speedup vs baseline: 1.4675x; 1.4675x over previous
//
#include <hip/hip_runtime.h>
#include <hip/hip_fp16.h>
#include <math.h>

#define BN_EPS 1e-5f

typedef _Float16 h2v __attribute__((ext_vector_type(2)));

__device__ __forceinline__ float max3f(float a, float b, float c) {
    return fmaxf(fmaxf(a, b), c);
}
__device__ __forceinline__ float fdot2u(uint32_t a, uint32_t b, float c) {
    union U { uint32_t u; h2v h; } ua, ub;
    ua.u = a; ub.u = b;
    return __builtin_amdgcn_fdot2(ua.h, ub.h, c, false);
}
__device__ __forceinline__ uint32_t pack2(float a, float b) {
    union U { uint32_t u; h2v h; } x;
    x.h.x = (_Float16)a; x.h.y = (_Float16)b; return x.u;
}

// One block per (b,c) plane. 512 threads = 8 waves. 4 blocks/CU resident.
// Phase A: streaming blurpool(maxpool3x3(x)), consume-layout loads + shfl.
// Phase B: four directional 33-tap convs via v_dot2_f32_f16 (fp16 pairs,
//          f32 accum); weights pre-packed to an LDS table once per block.
// Phase C: wave-local out = x * gate (no block sync after B).
// [r22 = r15 verbatim — best of 21 rounds at 156.5us graph. All overlap
//  variants (r9/r16/r17/r19/r21) regressed via spill or lost locality.]
__global__ __launch_bounds__(512, 8)
void mra_fused(const float* __restrict__ x,
               const float* __restrict__ wh1,
               const float* __restrict__ wv1,
               const float* __restrict__ wh2,
               const float* __restrict__ wv2,
               const float* __restrict__ bng,
               const float* __restrict__ bnb,
               const float* __restrict__ bnm,
               const float* __restrict__ bnv,
               float* __restrict__ out)
{
    __shared__ __align__(16) __half sxp_h[76][84];   // x_tem, 12.77 KB, zero halo
    __shared__ __align__(16) __half gate_h[64][72];  // gate, 9 KB
    __shared__ __align__(16) uint32_t wtab[13][12];  // packed fp16 weight pairs

    const int plane = blockIdx.x;       // b*256 + c
    const int c     = plane & 255;
    const int tid   = threadIdx.x;
    const int lane  = tid & 63;
    const int w     = tid >> 6;         // 0..7
    const float* __restrict__ xp = x   + (size_t)plane * 36864;
    float* __restrict__       op = out + (size_t)plane * 36864;

    const float* __restrict__ wh1p = wh1 + c * 33;
    const float* __restrict__ wv1p = wv1 + c * 33;
    const float* __restrict__ wh2p = wh2 + c * 33;
    const float* __restrict__ wv2p = wv2 + c * 33;

    // ---- zero x_tem plane (halo must be 0 for conv boundary) ----
    {
        int* z = (int*)&sxp_h[0][0];
        const int nInt = (76 * 84 * 2) / 4;   // 3192
        #pragma unroll
        for (int i = 0; i < 7; ++i) {
            const int idx = tid + (i << 9);
            if (idx < nInt) z[idx] = 0;
        }
    }
    // ---- pack fp16 weight-pair table (one thread per e-row) ----
    if (tid < 13) {
        const int e = tid - 6;
        uint32_t* wr = wtab[tid];
        #pragma unroll
        for (int s = 0; s < 12; ++s) wr[s] = 0;
        if (e >= -5 && e <= 5) {
            const float* a1 = wh1p + (e + 5) * 3;
            wr[0] = pack2(a1[0], a1[1]); wr[1] = pack2(a1[2], 0.f);
            const float* a2 = wh2p + (e + 5) * 3;
            wr[2] = pack2(a2[0], a2[1]); wr[3] = pack2(a2[2], 0.f);
        }
        if (e >= -4 && e <= 4) {
            wr[4] = pack2(wv2p[4 - e], wv2p[16 - e]);
            wr[5] = pack2(wv2p[28 - e], 0.f);
        } else if (e == 5)  wr[4] = pack2(wv2p[11], wv2p[23]);
        else if (e == -5)   wr[4] = pack2(wv2p[9],  wv2p[21]);
        else if (e == 6)    wr[4] = pack2(wv2p[22], 0.f);
        else                wr[4] = pack2(wv2p[10], 0.f);   // e == -6
        if (e >= -1 && e <= 1) {
            const float* a3 = wv1p + (e + 1) * 11;
            wr[6]  = pack2(a3[0], a3[1]); wr[7]  = pack2(a3[2], a3[3]);
            wr[8]  = pack2(a3[4], a3[5]); wr[9]  = pack2(a3[6], a3[7]);
            wr[10] = pack2(a3[8], a3[9]); wr[11] = pack2(a3[10], 0.f);
        }
    }
    __syncthreads();

    // ---- Phase A: streaming maxpool3x3(SAME) + blur4x4 stride-3 -> 64x64 ----
    {
        const int P0  = w << 3;
        const int r0  = 3 * P0 - 2;
        const int col = 3 * lane;

        float c0r[4], c1r[4], c2r[4];
        auto issue = [&](int k, int s) {
            int r = r0 + k;
            r = r < 0 ? 0 : (r > 191 ? 191 : r);   // clamp == maxpool SAME
            const float* rp = xp + r * 192 + col;
            c0r[s] = rp[0]; c1r[s] = rp[1]; c2r[s] = rp[2];
        };
        issue(0, 0); issue(1, 1); issue(2, 2); issue(3, 3);

        float h[3][4];
        float hb[3];
        float hbp = 0.f;

        #pragma unroll
        for (int k = 0; k < 27; ++k) {
            const int s = k & 3;
            const float c0 = c0r[s], c1 = c1r[s], c2 = c2r[s];
            if (k + 4 < 27) issue(k + 4, s);

            float xm2 = __shfl_up(c1, 1);
            float xm1 = __shfl_up(c2, 1);
            float xp3 = __shfl_down(c0, 1);
            if (lane == 0)  xm1 = c0;
            if (lane == 63) xp3 = c2;

            const float hm_m1 = max3f(xm2, xm1, c0);
            const float hm_0  = max3f(xm1, c0,  c1);
            const float hm_1  = max3f(c0,  c1,  c2);
            const float hm_2  = max3f(c1,  c2,  xp3);

            float* hk = h[k % 3];
            hk[0] = (lane == 0) ? hm_1 : hm_m1;  // reflect: center -1 == center 1
            hk[1] = hm_0; hk[2] = hm_1; hk[3] = hm_2;

            if (k >= 2) {
                const float* a = h[(k - 2) % 3];
                const float* b = h[(k - 1) % 3];
                const float* d = h[k % 3];
                const float e4 =
                      0.125f * max3f(a[0], b[0], d[0])
                    + 0.375f * max3f(a[1], b[1], d[1])
                    + 0.375f * max3f(a[2], b[2], d[2])
                    + 0.125f * max3f(a[3], b[3], d[3]);
                if (k == 2) {
                    hbp = e4;
                } else {
                    hb[k % 3] = e4;
                    if (k % 3 == 2) {
                        const int i = (k - 5) / 3;
                        float a_out;
                        if (i == 0 && w == 0)
                            a_out = 0.375f * hb[0] + 0.5f * hb[1] + 0.125f * hb[2];
                        else
                            a_out = 0.125f * hbp + 0.375f * hb[0]
                                  + 0.375f * hb[1] + 0.125f * hb[2];
                        hbp = hb[2];
                        sxp_h[(w << 3) + i + 6][lane + 8] = __float2half(a_out);
                    }
                }
            }
        }
    }
    __syncthreads();   // A -> B

    // ---- Phase B: four directional convs via fdot2 ----
    // thread: gate row p = tid>>3, cols q0..q0+7, q0 = 8*(tid&7)
    // data halves X(j) = sxp_h[p+e+6][q0+j], j=0..23
    // du[u]=(X(2u),X(2u+1)), su[u]=(X(2u+1),X(2u+2))
    const int p  = tid >> 3;
    const int q0 = (tid & 7) << 3;
    float acc[8];
    #pragma unroll
    for (int i = 0; i < 8; ++i) acc[i] = 0.0f;

    #pragma unroll
    for (int e = -6; e <= 6; ++e) {
        const uint2* drow = (const uint2*)&sxp_h[p + e + 6][q0];
        uint32_t du[12], su[11];
        #pragma unroll
        for (int u2 = 0; u2 < 6; ++u2) {
            const uint2 t = drow[u2];
            du[2 * u2] = t.x; du[2 * u2 + 1] = t.y;
        }
        #pragma unroll
        for (int u = 0; u < 11; ++u)
            su[u] = __builtin_amdgcn_alignbit(du[u + 1], du[u], 16);

        const uint2* wrow = (const uint2*)&wtab[e + 6][0];
        const uint2 wa = wrow[0], wb = wrow[1], wc = wrow[2];

        auto RUN3 = [&](float a, int j0, uint32_t pA, uint32_t pB) -> float {
            const int u = j0 >> 1;
            if (j0 & 1) { a = fdot2u(su[u], pA, a); a = fdot2u(su[u + 1], pB, a); }
            else        { a = fdot2u(du[u], pA, a); a = fdot2u(du[u + 1], pB, a); }
            return a;
        };
        auto RUN1 = [&](float a, int j0, uint32_t pA) -> float {
            const int u = j0 >> 1;
            return (j0 & 1) ? fdot2u(su[u], pA, a) : fdot2u(du[u], pA, a);
        };

        if (e >= -5 && e <= 5) {
            #pragma unroll
            for (int i = 0; i < 8; ++i) {
                acc[i] = RUN3(acc[i], i + 7, wa.x, wa.y);        // x_h1
                acc[i] = RUN3(acc[i], i + 7 - e, wb.x, wb.y);    // x_h2 (anti-diag)
            }
        }
        if (e >= -4 && e <= 4) {                                  // x_w2 (diag)
            #pragma unroll
            for (int i = 0; i < 8; ++i) acc[i] = RUN3(acc[i], i + 7 - e, wc.x, wc.y);
        } else if (e == 5) {
            #pragma unroll
            for (int i = 0; i < 8; ++i) acc[i] = RUN1(acc[i], i + 3, wc.x);
        } else if (e == -5) {
            // taps: dh=-1 -> j=i+12 (w=wv2p[9]), dh=0 -> j=i+13 (w=wv2p[21])
            #pragma unroll
            for (int i = 0; i < 8; ++i) acc[i] = RUN1(acc[i], i + 12, wc.x);
        } else if (e == 6) {
            #pragma unroll
            for (int i = 0; i < 8; ++i) acc[i] = RUN1(acc[i], i + 3, wc.x);
        } else {  // e == -6
            #pragma unroll
            for (int i = 0; i < 8; ++i) acc[i] = RUN1(acc[i], i + 13, wc.x);
        }
        if (e >= -1 && e <= 1) {                                  // x_w1
            const uint2 wd = wrow[3], we_ = wrow[4], wf_ = wrow[5];
            const uint32_t wp[6] = {wd.x, wd.y, we_.x, we_.y, wf_.x, wf_.y};
            #pragma unroll
            for (int i = 0; i < 8; ++i) {
                const int j0 = i + 3;
                const int u  = j0 >> 1;
                float a = acc[i];
                #pragma unroll
                for (int kk = 0; kk < 6; ++kk)
                    a = (j0 & 1) ? fdot2u(su[u + kk], wp[kk], a)
                                 : fdot2u(du[u + kk], wp[kk], a);
                acc[i] = a;
            }
        }
    }

    // ---- BN + sigmoid -> gate buffer (separate LDS; no overwrite hazard) ----
    const float inv = bng[c] * rsqrtf(bnv[c] + BN_EPS);
    const float mu  = bnm[c];
    const float bt  = bnb[c];
    #pragma unroll
    for (int i = 0; i < 4; ++i) {
        const float a0 = (acc[2 * i]     - mu) * inv + bt;
        const float a1 = (acc[2 * i + 1] - mu) * inv + bt;
        const float g0 = 1.0f / (1.0f + __expf(-a0));
        const float g1 = 1.0f / (1.0f + __expf(-a1));
        *(__half2*)(&gate_h[p][q0 + 2 * i]) = __floats2half2_rn(g0, g1);
    }
    __builtin_amdgcn_wave_barrier();   // order BN ds_writes before C ds_reads

    // ---- Phase C (wave-local): out rows 24w..24w+23 = x * gate ----
    const float4* __restrict__ x4 = (const float4*)xp + w * 1152;  // 24*48
    float4* __restrict__       o4 = (float4*)op       + w * 1152;
    int rlj[3], gcj[3], rrj[3];
    #pragma unroll
    for (int j = 0; j < 3; ++j) {
        const int idx0 = lane + (j << 6);
        const int rw   = idx0 / 48;            // 0..3
        const int c4   = idx0 - rw * 48;
        rlj[j] = rw;
        const int jb = c4 << 2;
        gcj[j] = jb / 3;
        rrj[j] = jb - 3 * gcj[j];
    }
    #pragma unroll
    for (int u = 0; u < 6; ++u) {
        #pragma unroll
        for (int j = 0; j < 3; ++j) {
            const int row_l = rlj[j] + (u << 2);       // 0..23
            const int idx   = lane + ((u * 3 + j) << 6);
            const int gr    = (w << 3) + row_l / 3;    // gate row 8w..8w+7
            const float g0 = __half2float(gate_h[gr][gcj[j]]);
            const float g1 = __half2float(gate_h[gr][gcj[j] + 1]);
            const float4 xv = x4[idx];
            float4 ov;
            const float s1 = (rrj[j] == 2) ? g1 : g0;
            const float s2 = (rrj[j] >= 1) ? g1 : g0;
            ov.x = xv.x * g0;
            ov.y = xv.y * s1;
            ov.z = xv.z * s2;
            ov.w = xv.w * g1;
            o4[idx] = ov;
        }
    }
}

extern "C" void kernel_launch(void* const* d_in, const int* in_sizes, int n_in,
                              void* d_out, int out_size, void* d_ws, size_t ws_size,
                              hipStream_t stream) {
    const float* x   = (const float*)d_in[0];
    const float* wh1 = (const float*)d_in[1];
    const float* wv1 = (const float*)d_in[2];
    const float* wh2 = (const float*)d_in[3];
    const float* wv2 = (const float*)d_in[4];
    const float* g   = (const float*)d_in[5];
    const float* b   = (const float*)d_in[6];
    const float* m   = (const float*)d_in[7];
    const float* v   = (const float*)d_in[8];

    mra_fused<<<dim3(8 * 256), dim3(512), 0, stream>>>(
        x, wh1, wv1, wh2, wv2, g, b, m, v, (float*)d_out);
}

// Round 23
// 149.828 us; speedup vs baseline: 1.5309x; 1.0432x over previous
//
#include <hip/hip_runtime.h>
#include <hip/hip_fp16.h>
#include <math.h>

#define BN_EPS 1e-5f

typedef _Float16 h2v __attribute__((ext_vector_type(2)));

__device__ __forceinline__ float max3f(float a, float b, float c) {
    return fmaxf(fmaxf(a, b), c);
}
__device__ __forceinline__ float fdot2u(uint32_t a, uint32_t b, float c) {
    union U { uint32_t u; h2v h; } ua, ub;
    ua.u = a; ub.u = b;
    return __builtin_amdgcn_fdot2(ua.h, ub.h, c, false);
}
__device__ __forceinline__ uint32_t pack2(float a, float b) {
    union U { uint32_t u; h2v h; } x;
    x.h.x = (_Float16)a; x.h.y = (_Float16)b; return x.u;
}

// One block per (b,c) plane. 512 threads = 8 waves. 4 blocks/CU resident.
// Phase A: streaming blurpool(maxpool3x3(x)), consume-layout loads + shfl,
//          8-deep prefetch ring (r15 was 4-deep; HBM latency ~900cy vs
//          ~400cy of cover -> latency-stalled; 8-deep covers ~800cy).
// Phase B: four directional 33-tap convs via v_dot2_f32_f16.
// Phase C: wave-local out = x * gate (no block sync after B).
__global__ __launch_bounds__(512, 8)
void mra_fused(const float* __restrict__ x,
               const float* __restrict__ wh1,
               const float* __restrict__ wv1,
               const float* __restrict__ wh2,
               const float* __restrict__ wv2,
               const float* __restrict__ bng,
               const float* __restrict__ bnb,
               const float* __restrict__ bnm,
               const float* __restrict__ bnv,
               float* __restrict__ out)
{
    __shared__ __align__(16) __half sxp_h[76][84];   // x_tem, 12.77 KB, zero halo
    __shared__ __align__(16) __half gate_h[64][72];  // gate, 9 KB
    __shared__ __align__(16) uint32_t wtab[13][12];  // packed fp16 weight pairs

    const int plane = blockIdx.x;       // b*256 + c
    const int c     = plane & 255;
    const int tid   = threadIdx.x;
    const int lane  = tid & 63;
    const int w     = tid >> 6;         // 0..7
    const float* __restrict__ xp = x   + (size_t)plane * 36864;
    float* __restrict__       op = out + (size_t)plane * 36864;

    const float* __restrict__ wh1p = wh1 + c * 33;
    const float* __restrict__ wv1p = wv1 + c * 33;
    const float* __restrict__ wh2p = wh2 + c * 33;
    const float* __restrict__ wv2p = wv2 + c * 33;

    // ---- zero x_tem plane (halo must be 0 for conv boundary) ----
    {
        int* z = (int*)&sxp_h[0][0];
        const int nInt = (76 * 84 * 2) / 4;   // 3192
        #pragma unroll
        for (int i = 0; i < 7; ++i) {
            const int idx = tid + (i << 9);
            if (idx < nInt) z[idx] = 0;
        }
    }
    // ---- pack fp16 weight-pair table (one thread per e-row) ----
    if (tid < 13) {
        const int e = tid - 6;
        uint32_t* wr = wtab[tid];
        #pragma unroll
        for (int s = 0; s < 12; ++s) wr[s] = 0;
        if (e >= -5 && e <= 5) {
            const float* a1 = wh1p + (e + 5) * 3;
            wr[0] = pack2(a1[0], a1[1]); wr[1] = pack2(a1[2], 0.f);
            const float* a2 = wh2p + (e + 5) * 3;
            wr[2] = pack2(a2[0], a2[1]); wr[3] = pack2(a2[2], 0.f);
        }
        if (e >= -4 && e <= 4) {
            wr[4] = pack2(wv2p[4 - e], wv2p[16 - e]);
            wr[5] = pack2(wv2p[28 - e], 0.f);
        } else if (e == 5)  wr[4] = pack2(wv2p[11], wv2p[23]);
        else if (e == -5)   wr[4] = pack2(wv2p[9],  wv2p[21]);
        else if (e == 6)    wr[4] = pack2(wv2p[22], 0.f);
        else                wr[4] = pack2(wv2p[10], 0.f);   // e == -6
        if (e >= -1 && e <= 1) {
            const float* a3 = wv1p + (e + 1) * 11;
            wr[6]  = pack2(a3[0], a3[1]); wr[7]  = pack2(a3[2], a3[3]);
            wr[8]  = pack2(a3[4], a3[5]); wr[9]  = pack2(a3[6], a3[7]);
            wr[10] = pack2(a3[8], a3[9]); wr[11] = pack2(a3[10], 0.f);
        }
    }
    __syncthreads();

    // ---- Phase A: streaming maxpool3x3(SAME) + blur4x4 stride-3 -> 64x64 ----
    {
        const int P0  = w << 3;
        const int r0  = 3 * P0 - 2;
        const int col = 3 * lane;

        float c0r[8], c1r[8], c2r[8];    // 8-deep prefetch ring
        auto issue = [&](int k, int s) {
            int r = r0 + k;
            r = r < 0 ? 0 : (r > 191 ? 191 : r);   // clamp == maxpool SAME
            const float* rp = xp + r * 192 + col;
            c0r[s] = rp[0]; c1r[s] = rp[1]; c2r[s] = rp[2];
        };
        #pragma unroll
        for (int k = 0; k < 8; ++k) issue(k, k);

        float h[3][4];
        float hb[3];
        float hbp = 0.f;

        #pragma unroll
        for (int k = 0; k < 27; ++k) {
            const int s = k & 7;
            const float c0 = c0r[s], c1 = c1r[s], c2 = c2r[s];
            if (k + 8 < 27) issue(k + 8, s);

            float xm2 = __shfl_up(c1, 1);
            float xm1 = __shfl_up(c2, 1);
            float xp3 = __shfl_down(c0, 1);
            if (lane == 0)  xm1 = c0;
            if (lane == 63) xp3 = c2;

            const float hm_m1 = max3f(xm2, xm1, c0);
            const float hm_0  = max3f(xm1, c0,  c1);
            const float hm_1  = max3f(c0,  c1,  c2);
            const float hm_2  = max3f(c1,  c2,  xp3);

            float* hk = h[k % 3];
            hk[0] = (lane == 0) ? hm_1 : hm_m1;  // reflect: center -1 == center 1
            hk[1] = hm_0; hk[2] = hm_1; hk[3] = hm_2;

            if (k >= 2) {
                const float* a = h[(k - 2) % 3];
                const float* b = h[(k - 1) % 3];
                const float* d = h[k % 3];
                const float e4 =
                      0.125f * max3f(a[0], b[0], d[0])
                    + 0.375f * max3f(a[1], b[1], d[1])
                    + 0.375f * max3f(a[2], b[2], d[2])
                    + 0.125f * max3f(a[3], b[3], d[3]);
                if (k == 2) {
                    hbp = e4;
                } else {
                    hb[k % 3] = e4;
                    if (k % 3 == 2) {
                        const int i = (k - 5) / 3;
                        float a_out;
                        if (i == 0 && w == 0)
                            a_out = 0.375f * hb[0] + 0.5f * hb[1] + 0.125f * hb[2];
                        else
                            a_out = 0.125f * hbp + 0.375f * hb[0]
                                  + 0.375f * hb[1] + 0.125f * hb[2];
                        hbp = hb[2];
                        sxp_h[(w << 3) + i + 6][lane + 8] = __float2half(a_out);
                    }
                }
            }
        }
    }
    __syncthreads();   // A -> B

    // ---- Phase B: four directional convs via fdot2 ----
    const int p  = tid >> 3;
    const int q0 = (tid & 7) << 3;
    float acc[8];
    #pragma unroll
    for (int i = 0; i < 8; ++i) acc[i] = 0.0f;

    #pragma unroll
    for (int e = -6; e <= 6; ++e) {
        const uint2* drow = (const uint2*)&sxp_h[p + e + 6][q0];
        uint32_t du[12], su[11];
        #pragma unroll
        for (int u2 = 0; u2 < 6; ++u2) {
            const uint2 t = drow[u2];
            du[2 * u2] = t.x; du[2 * u2 + 1] = t.y;
        }
        #pragma unroll
        for (int u = 0; u < 11; ++u)
            su[u] = __builtin_amdgcn_alignbit(du[u + 1], du[u], 16);

        const uint2* wrow = (const uint2*)&wtab[e + 6][0];
        const uint2 wa = wrow[0], wb = wrow[1], wc = wrow[2];

        auto RUN3 = [&](float a, int j0, uint32_t pA, uint32_t pB) -> float {
            const int u = j0 >> 1;
            if (j0 & 1) { a = fdot2u(su[u], pA, a); a = fdot2u(su[u + 1], pB, a); }
            else        { a = fdot2u(du[u], pA, a); a = fdot2u(du[u + 1], pB, a); }
            return a;
        };
        auto RUN1 = [&](float a, int j0, uint32_t pA) -> float {
            const int u = j0 >> 1;
            return (j0 & 1) ? fdot2u(su[u], pA, a) : fdot2u(du[u], pA, a);
        };

        if (e >= -5 && e <= 5) {
            #pragma unroll
            for (int i = 0; i < 8; ++i) {
                acc[i] = RUN3(acc[i], i + 7, wa.x, wa.y);        // x_h1
                acc[i] = RUN3(acc[i], i + 7 - e, wb.x, wb.y);    // x_h2 (anti-diag)
            }
        }
        if (e >= -4 && e <= 4) {                                  // x_w2 (diag)
            #pragma unroll
            for (int i = 0; i < 8; ++i) acc[i] = RUN3(acc[i], i + 7 - e, wc.x, wc.y);
        } else if (e == 5) {
            #pragma unroll
            for (int i = 0; i < 8; ++i) acc[i] = RUN1(acc[i], i + 3, wc.x);
        } else if (e == -5) {
            // taps: dh=-1 -> j=i+12 (w=wv2p[9]), dh=0 -> j=i+13 (w=wv2p[21])
            #pragma unroll
            for (int i = 0; i < 8; ++i) acc[i] = RUN1(acc[i], i + 12, wc.x);
        } else if (e == 6) {
            #pragma unroll
            for (int i = 0; i < 8; ++i) acc[i] = RUN1(acc[i], i + 3, wc.x);
        } else {  // e == -6
            #pragma unroll
            for (int i = 0; i < 8; ++i) acc[i] = RUN1(acc[i], i + 13, wc.x);
        }
        if (e >= -1 && e <= 1) {                                  // x_w1
            const uint2 wd = wrow[3], we_ = wrow[4], wf_ = wrow[5];
            const uint32_t wp[6] = {wd.x, wd.y, we_.x, we_.y, wf_.x, wf_.y};
            #pragma unroll
            for (int i = 0; i < 8; ++i) {
                const int j0 = i + 3;
                const int u  = j0 >> 1;
                float a = acc[i];
                #pragma unroll
                for (int kk = 0; kk < 6; ++kk)
                    a = (j0 & 1) ? fdot2u(su[u + kk], wp[kk], a)
                                 : fdot2u(du[u + kk], wp[kk], a);
                acc[i] = a;
            }
        }
    }

    // ---- BN + sigmoid -> gate buffer (separate LDS; no overwrite hazard) ----
    const float inv = bng[c] * rsqrtf(bnv[c] + BN_EPS);
    const float mu  = bnm[c];
    const float bt  = bnb[c];
    #pragma unroll
    for (int i = 0; i < 4; ++i) {
        const float a0 = (acc[2 * i]     - mu) * inv + bt;
        const float a1 = (acc[2 * i + 1] - mu) * inv + bt;
        const float g0 = 1.0f / (1.0f + __expf(-a0));
        const float g1 = 1.0f / (1.0f + __expf(-a1));
        *(__half2*)(&gate_h[p][q0 + 2 * i]) = __floats2half2_rn(g0, g1);
    }
    __builtin_amdgcn_wave_barrier();   // order BN ds_writes before C ds_reads

    // ---- Phase C (wave-local): out rows 24w..24w+23 = x * gate ----
    const float4* __restrict__ x4 = (const float4*)xp + w * 1152;  // 24*48
    float4* __restrict__       o4 = (float4*)op       + w * 1152;
    int rlj[3], gcj[3], rrj[3];
    #pragma unroll
    for (int j = 0; j < 3; ++j) {
        const int idx0 = lane + (j << 6);
        const int rw   = idx0 / 48;            // 0..3
        const int c4   = idx0 - rw * 48;
        rlj[j] = rw;
        const int jb = c4 << 2;
        gcj[j] = jb / 3;
        rrj[j] = jb - 3 * gcj[j];
    }
    #pragma unroll
    for (int u = 0; u < 6; ++u) {
        #pragma unroll
        for (int j = 0; j < 3; ++j) {
            const int row_l = rlj[j] + (u << 2);       // 0..23
            const int idx   = lane + ((u * 3 + j) << 6);
            const int gr    = (w << 3) + row_l / 3;    // gate row 8w..8w+7
            const float g0 = __half2float(gate_h[gr][gcj[j]]);
            const float g1 = __half2float(gate_h[gr][gcj[j] + 1]);
            const float4 xv = x4[idx];
            float4 ov;
            const float s1 = (rrj[j] == 2) ? g1 : g0;
            const float s2 = (rrj[j] >= 1) ? g1 : g0;
            ov.x = xv.x * g0;
            ov.y = xv.y * s1;
            ov.z = xv.z * s2;
            ov.w = xv.w * g1;
            o4[idx] = ov;
        }
    }
}

extern "C" void kernel_launch(void* const* d_in, const int* in_sizes, int n_in,
                              void* d_out, int out_size, void* d_ws, size_t ws_size,
                              hipStream_t stream) {
    const float* x   = (const float*)d_in[0];
    const float* wh1 = (const float*)d_in[1];
    const float* wv1 = (const float*)d_in[2];
    const float* wh2 = (const float*)d_in[3];
    const float* wv2 = (const float*)d_in[4];
    const float* g   = (const float*)d_in[5];
    const float* b   = (const float*)d_in[6];
    const float* m   = (const float*)d_in[7];
    const float* v   = (const float*)d_in[8];

    mra_fused<<<dim3(8 * 256), dim3(512), 0, stream>>>(
        x, wh1, wv1, wh2, wv2, g, b, m, v, (float*)d_out);
}